// Round 5
// baseline (365.889 us; speedup 1.0000x reference)
//
#include <hip/hip_runtime.h>
#include <hip/hip_bf16.h>
#include <hip/hip_fp16.h>
#include <math.h>

// ---------------------------------------------------------------------------
// DisplacementTensors: rad = MLP(radial_encode(|r|)) depends only on |r| ->
// tabulate [F(d) | F(d)@w_v | F(d)@w_d] (96 f32/row, 8192 nearest-neighbor
// entries, 3 MB, L2-resident).  k_table: one lane per entry, activations in
// registers (full unroll), weights via uniform scalar loads from a
// pre-converted f32 concat buffer.  CSR segment-sum: hist -> scan(+cursor) ->
// place packed 8B payload (f16 rs | u16 idx) in CSR order -> 2 waves per node
// stream contiguous halves, LDS-reduce, write outputs directly.
// dtype (bf16 vs f32) detected per-block by probing r_ij halfwords.
// ---------------------------------------------------------------------------

#define TSIZE 8192
#define DMAX  2.0f           // RBF centers <=1, width 1/8 -> F const beyond ~2
#define NODES_PB 4           // nodes per k_nodes block (2 waves each -> 512 thr)

// f32 concat-weight offsets (floats)
#define O_WRAD 0
#define O_BRAD 256
#define O_WDIR 288
#define O_W1   1312
#define O_B1   3360
#define O_W2   3424
#define O_B2   7520
#define O_W3   7584
#define O_B3   9632
#define O_WV   9664
#define O_WD   10688
#define W_TOT  11712

__device__ __forceinline__ float lrelu(float x) { return x > 0.0f ? x : 0.1f * x; }

__device__ __forceinline__ float ldf(const void* p, int i, bool f32) {
    return f32 ? ((const float*)p)[i]
               : __uint_as_float(((unsigned int)((const unsigned short*)p)[i]) << 16);
}
__device__ __forceinline__ void stf(void* p, size_t i, float v, bool f32) {
    if (f32) ((float*)p)[i] = v;
    else     ((__hip_bfloat16*)p)[i] = __float2bfloat16(v);
}

// probe first 128 halfwords of r_ij as bf16: f32 data's low halves have random
// exponents -> some value is non-finite/huge with P ~ 1-1e-16.  Uniform per
// thread (same addresses), so no sync needed.
__device__ __forceinline__ bool detect_f32(const void* r) {
    const unsigned short* p = (const unsigned short*)r;
    int bad = 0;
#pragma unroll 8
    for (int i = 0; i < 128; i++) {
        float v = __uint_as_float(((unsigned int)p[i]) << 16);
        bad |= (!isfinite(v) || fabsf(v) > 1e5f) ? 1 : 0;
    }
    return bad != 0;
}

// --- fused prep: flag store | weight->f32 concat | zero counts -------------
__global__ void k_prep(const void* __restrict__ r_ij,
                       const void* w_rad, const void* b_rad, const void* w_direct,
                       const void* w1, const void* b1, const void* w2, const void* b2,
                       const void* w3, const void* b3, const void* w_v, const void* w_d,
                       float* __restrict__ wcat, int* __restrict__ flag,
                       int* __restrict__ counts, int N) {
    const int b = blockIdx.x;
    if (b == 0) {
        if (threadIdx.x == 0) flag[0] = detect_f32(r_ij) ? 1 : 0;
    } else if (b <= 11) {
        const bool f32 = detect_f32(r_ij);
        const void* src; int cnt; int off;
        switch (b) {
            case 1:  src = w_rad;    cnt = 256;  off = O_WRAD; break;
            case 2:  src = b_rad;    cnt = 32;   off = O_BRAD; break;
            case 3:  src = w_direct; cnt = 1024; off = O_WDIR; break;
            case 4:  src = w1;       cnt = 2048; off = O_W1;   break;
            case 5:  src = b1;       cnt = 64;   off = O_B1;   break;
            case 6:  src = w2;       cnt = 4096; off = O_W2;   break;
            case 7:  src = b2;       cnt = 64;   off = O_B2;   break;
            case 8:  src = w3;       cnt = 2048; off = O_W3;   break;
            case 9:  src = b3;       cnt = 32;   off = O_B3;   break;
            case 10: src = w_v;      cnt = 1024; off = O_WV;   break;
            default: src = w_d;      cnt = 1024; off = O_WD;   break;
        }
        for (int i = threadIdx.x; i < cnt; i += blockDim.x)
            wcat[off + i] = ldf(src, i, f32);
    } else {
        int i = (b - 12) * blockDim.x + threadIdx.x;
        if (i < N) counts[i] = 0;
    }
}

// --- LUT build: one lane per entry, register activations, scalar weights ---
__global__ void __launch_bounds__(256) k_table(const float* __restrict__ wcat,
                                               float* __restrict__ tabI) {
    const int e = blockIdx.x * 256 + threadIdx.x;       // 0..TSIZE-1
    const float d = (float)e * (DMAX / (float)(TSIZE - 1));

    float enc[8];
#pragma unroll
    for (int k = 0; k < 8; k++) {
        float t = (d - (float)k * (1.0f / 7.0f)) * 8.0f;
        enc[k] = expf(-t * t);
    }

    float h[32];
#pragma unroll
    for (int j = 0; j < 32; j++) {
        float s = wcat[O_BRAD + j];
#pragma unroll
        for (int k = 0; k < 8; k++) s = fmaf(enc[k], wcat[O_WRAD + k * 32 + j], s);
        h[j] = s;
    }

    float t1[64];
#pragma unroll
    for (int j = 0; j < 64; j++) {
        float s = wcat[O_B1 + j];
#pragma unroll
        for (int i = 0; i < 32; i++) s = fmaf(h[i], wcat[O_W1 + i * 64 + j], s);
        t1[j] = lrelu(s);
    }

    float t2[64];
#pragma unroll
    for (int j = 0; j < 64; j++) {
        float s = wcat[O_B2 + j];
#pragma unroll
        for (int i = 0; i < 64; i++) s = fmaf(t1[i], wcat[O_W2 + i * 64 + j], s);
        t2[j] = lrelu(s);
    }

    float rad[32];
#pragma unroll
    for (int j = 0; j < 32; j++) {
        float s = wcat[O_B3 + j];
#pragma unroll
        for (int i = 0; i < 64; i++) s = fmaf(t2[i], wcat[O_W3 + i * 32 + j], s);
#pragma unroll
        for (int i = 0; i < 32; i++) s = fmaf(h[i], wcat[O_WDIR + i * 32 + j], s);
        rad[j] = s;
        tabI[e * 96 + j] = s;
    }

#pragma unroll
    for (int j = 0; j < 32; j++) {
        float sv = 0.0f, sd = 0.0f;
#pragma unroll
        for (int i = 0; i < 32; i++) {
            sv = fmaf(rad[i], wcat[O_WV + i * 32 + j], sv);
            sd = fmaf(rad[i], wcat[O_WD + i * 32 + j], sd);
        }
        tabI[e * 96 + 32 + j] = sv;
        tabI[e * 96 + 64 + j] = sd;
    }
}

// --- CSR construction ------------------------------------------------------
__global__ void k_hist(const int* __restrict__ src, int* __restrict__ counts, int E) {
    int e = blockIdx.x * blockDim.x + threadIdx.x;
    if (e < E) atomicAdd(&counts[src[e]], 1);
}

__global__ void k_scan(const int* __restrict__ counts, int* __restrict__ rowstart,
                       int* __restrict__ cursor, int N, int E) {
    __shared__ int part[1024];
    const int t = threadIdx.x;
    const int CH = (N + 1023) / 1024;
    const int lo = t * CH;
    const int hi = min(lo + CH, N);

    int s = 0;
    for (int i = lo; i < hi; i++) s += counts[i];
    part[t] = s;
    __syncthreads();

    for (int off = 1; off < 1024; off <<= 1) {
        int v = part[t];
        int w = (t >= off) ? part[t - off] : 0;
        __syncthreads();
        part[t] = v + w;
        __syncthreads();
    }

    int run = (t == 0) ? 0 : part[t - 1];
    for (int i = lo; i < hi; i++) {
        rowstart[i] = run;
        cursor[i] = run;
        run += counts[i];
    }
    if (t == 0) rowstart[N] = E;
}

// place packed payload into CSR slot via cursor atomic (fast path),
// or just the permutation (fallback)
__global__ void k_place(const int* __restrict__ src, int* __restrict__ cursor,
                        const void* __restrict__ r_ij, const int* __restrict__ flag,
                        uint2* __restrict__ eps, int* __restrict__ perm, int E) {
    int e = blockIdx.x * blockDim.x + threadIdx.x;
    if (e >= E) return;
    const int pos = atomicAdd(&cursor[src[e]], 1);
    if (eps) {
        const bool f32 = flag[0] != 0;
        const float x = ldf(r_ij, 3 * e + 0, f32);
        const float y = ldf(r_ij, 3 * e + 1, f32);
        const float z = ldf(r_ij, 3 * e + 2, f32);
        const float d2 = x * x + y * y + z * z;
        const float inv = rsqrtf(1.0f + 49.0f * d2);     // tens_sigmoid(7*r)
        const float u = fminf(sqrtf(d2), DMAX) * ((float)(TSIZE - 1) / DMAX);
        const unsigned int ti = (unsigned int)(u + 0.5f); // nearest, <= TSIZE-1
        const unsigned int h0 = __half_as_ushort(__float2half(7.0f * x * inv));
        const unsigned int h1 = __half_as_ushort(__float2half(7.0f * y * inv));
        const unsigned int h2 = __half_as_ushort(__float2half(7.0f * z * inv));
        eps[pos] = make_uint2(h0 | (h1 << 16), h2 | (ti << 16));
    } else {
        perm[pos] = e;
    }
}

// --- per-node accumulation: 2 waves per node, LDS reduce -------------------
// lane = (a = lane&31) x (half = lane>>5); branch-free accumulate:
// b1 = (half? rd : rv)*(half? rs1 : 1);  b2 = rd*(half? rs2 : rs0).
__global__ void __launch_bounds__(64 * 2 * NODES_PB) k_nodes(
    const uint2* __restrict__ eps,
    const int* __restrict__ perm,
    const void* __restrict__ r_ij,
    const int* __restrict__ rowstart,
    const float* __restrict__ tabI,
    const int* __restrict__ flag,
    void* __restrict__ out, int N) {
    __shared__ float red[NODES_PB][64][7];

    const int tid   = threadIdx.x;
    const int lane  = tid & 63;
    const int wv    = tid >> 6;          // 0..7
    const int nslot = wv >> 1;           // node slot 0..3
    const int wpart = wv & 1;            // which edge half
    const int n = blockIdx.x * NODES_PB + nslot;
    const int a = lane & 31;
    const bool hi = (lane >> 5) != 0;
    const bool f32 = flag[0] != 0;

    int s0 = 0, s1 = 0;
    if (n < N) { s0 = rowstart[n]; s1 = rowstart[n + 1]; }
    const int len = s1 - s0;
    const int hl = (len + 1) >> 1;
    const int lo = s0 + wpart * hl;
    const int up = wpart ? s1 : (s0 + hl);

    float accR = 0.f, acc1 = 0.f, acc2 = 0.f, acc3 = 0.f,
          acc4 = 0.f, acc5 = 0.f, acc6 = 0.f;

    if (eps) {
        int idx = lo;
        for (; idx + 1 < up; idx += 2) {          // unroll x2: overlap loads
            const uint2 qa = eps[idx];
            const uint2 qb = eps[idx + 1];
            const float ax = __half2float(__ushort_as_half((unsigned short)(qa.x & 0xffff)));
            const float ay = __half2float(__ushort_as_half((unsigned short)(qa.x >> 16)));
            const float az = __half2float(__ushort_as_half((unsigned short)(qa.y & 0xffff)));
            const int   ab = (int)(qa.y >> 16) * 96 + a;
            const float bx = __half2float(__ushort_as_half((unsigned short)(qb.x & 0xffff)));
            const float by = __half2float(__ushort_as_half((unsigned short)(qb.x >> 16)));
            const float bz = __half2float(__ushort_as_half((unsigned short)(qb.y & 0xffff)));
            const int   bb = (int)(qb.y >> 16) * 96 + a;

            const float raA = tabI[ab], rvA = tabI[ab + 32], rdA = tabI[ab + 64];
            const float raB = tabI[bb], rvB = tabI[bb + 32], rdB = tabI[bb + 64];

            const float b1A = (hi ? rdA : rvA) * (hi ? ay : 1.0f);
            const float b2A = rdA * (hi ? az : ax);
            const float b1B = (hi ? rdB : rvB) * (hi ? by : 1.0f);
            const float b2B = rdB * (hi ? bz : bx);

            accR += raA + raB;
            acc1 += b1A * ax + b1B * bx;
            acc2 += b1A * ay + b1B * by;
            acc3 += b1A * az + b1B * bz;
            acc4 += b2A * ax + b2B * bx;
            acc5 += b2A * ay + b2B * by;
            acc6 += b2A * az + b2B * bz;
        }
        if (idx < up) {
            const uint2 q = eps[idx];
            const float x = __half2float(__ushort_as_half((unsigned short)(q.x & 0xffff)));
            const float y = __half2float(__ushort_as_half((unsigned short)(q.x >> 16)));
            const float z = __half2float(__ushort_as_half((unsigned short)(q.y & 0xffff)));
            const int   b = (int)(q.y >> 16) * 96 + a;
            const float ra = tabI[b], rv = tabI[b + 32], rd = tabI[b + 64];
            const float b1 = (hi ? rd : rv) * (hi ? y : 1.0f);
            const float b2 = rd * (hi ? z : x);
            accR += ra;
            acc1 += b1 * x; acc2 += b1 * y; acc3 += b1 * z;
            acc4 += b2 * x; acc5 += b2 * y; acc6 += b2 * z;
        }
    } else {
        for (int idx = lo; idx < up; idx++) {
            const int e = perm[idx];
            const float x0 = ldf(r_ij, 3 * e + 0, f32);
            const float y0 = ldf(r_ij, 3 * e + 1, f32);
            const float z0 = ldf(r_ij, 3 * e + 2, f32);
            const float d2 = x0 * x0 + y0 * y0 + z0 * z0;
            const float inv = rsqrtf(1.0f + 49.0f * d2);
            const float x = 7.0f * x0 * inv, y = 7.0f * y0 * inv, z = 7.0f * z0 * inv;
            const float u = fminf(sqrtf(d2), DMAX) * ((float)(TSIZE - 1) / DMAX);
            const int b = (int)(u + 0.5f) * 96 + a;
            const float ra = tabI[b], rv = tabI[b + 32], rd = tabI[b + 64];
            const float b1 = (hi ? rd : rv) * (hi ? y : 1.0f);
            const float b2 = rd * (hi ? z : x);
            accR += ra;
            acc1 += b1 * x; acc2 += b1 * y; acc3 += b1 * z;
            acc4 += b2 * x; acc5 += b2 * y; acc6 += b2 * z;
        }
    }

    if (wpart == 1) {
        red[nslot][lane][0] = accR;
        red[nslot][lane][1] = acc1;
        red[nslot][lane][2] = acc2;
        red[nslot][lane][3] = acc3;
        red[nslot][lane][4] = acc4;
        red[nslot][lane][5] = acc5;
        red[nslot][lane][6] = acc6;
    }
    __syncthreads();
    if (wpart == 1 || n >= N) return;

    accR += red[nslot][lane][0];
    acc1 += red[nslot][lane][1];
    acc2 += red[nslot][lane][2];
    acc3 += red[nslot][lane][3];
    acc4 += red[nslot][lane][4];
    acc5 += red[nslot][lane][5];
    acc6 += red[nslot][lane][6];

    const size_t baseV = (size_t)N * 32;
    const size_t baseD = (size_t)N * 128;
    if (!hi) {
        stf(out, (size_t)n * 32 + a, accR, f32);
        const size_t vb = baseV + (size_t)n * 96 + a * 3;
        stf(out, vb + 0, acc1, f32);
        stf(out, vb + 1, acc2, f32);
        stf(out, vb + 2, acc3, f32);
        const size_t db = baseD + (size_t)n * 288 + a * 9;
        stf(out, db + 0, acc4, f32);
        stf(out, db + 1, acc5, f32);
        stf(out, db + 2, acc6, f32);
    } else {
        const size_t db = baseD + (size_t)n * 288 + a * 9;
        stf(out, db + 3, acc1, f32);
        stf(out, db + 4, acc2, f32);
        stf(out, db + 5, acc3, f32);
        stf(out, db + 6, acc4, f32);
        stf(out, db + 7, acc5, f32);
        stf(out, db + 8, acc6, f32);
    }
}

extern "C" void kernel_launch(void* const* d_in, const int* in_sizes, int n_in,
                              void* d_out, int out_size, void* d_ws, size_t ws_size,
                              hipStream_t stream) {
    const void* r_ij     = d_in[0];
    const void* w_rad    = d_in[1];
    const void* b_rad    = d_in[2];
    const void* w_direct = d_in[3];
    const void* w1       = d_in[4];
    const void* b1       = d_in[5];
    const void* w2       = d_in[6];
    const void* b2       = d_in[7];
    const void* w3       = d_in[8];
    const void* b3       = d_in[9];
    const void* w_v      = d_in[10];
    const void* w_d      = d_in[11];
    const int* edges_src = (const int*)d_in[12];

    const int E = in_sizes[12];
    const int N = out_size / 416;   // 32 + 96 + 288 per node

    // fixed region (after the eps/perm slot): wcat, flag, tabI, counts,
    // rowstart, cursor
    const size_t fixedInts = (size_t)W_TOT + 4 + (size_t)TSIZE * 96
                           + (size_t)N + (size_t)(N + 1) + (size_t)N;
    const size_t epsBytes  = (size_t)E * 8;
    const bool use_eps = ws_size >= epsBytes + fixedInts * 4 + 64;

    char* w = (char*)d_ws;
    uint2* eps = use_eps ? (uint2*)w : nullptr;
    int* perm  = use_eps ? nullptr : (int*)w;           // fallback slot
    const size_t slotBytes = use_eps ? epsBytes : (size_t)E * 4;

    float* wcat   = (float*)(w + ((slotBytes + 15) & ~(size_t)15));
    int* flag     = (int*)(wcat + W_TOT);
    float* tabI   = (float*)(flag + 4);
    int* counts   = (int*)(tabI + (size_t)TSIZE * 96);
    int* rowstart = counts + N;           // N+1
    int* cursor   = rowstart + N + 1;     // N

    k_prep<<<12 + (N + 255) / 256, 256, 0, stream>>>(
        r_ij, w_rad, b_rad, w_direct, w1, b1, w2, b2, w3, b3, w_v, w_d,
        wcat, flag, counts, N);
    k_table<<<TSIZE / 256, 256, 0, stream>>>(wcat, tabI);
    k_hist<<<(E + 255) / 256, 256, 0, stream>>>(edges_src, counts, E);
    k_scan<<<1, 1024, 0, stream>>>(counts, rowstart, cursor, N, E);
    k_place<<<(E + 255) / 256, 256, 0, stream>>>(edges_src, cursor, r_ij, flag,
                                                 eps, perm, E);
    k_nodes<<<(N + NODES_PB - 1) / NODES_PB, 64 * 2 * NODES_PB, 0, stream>>>(
        eps, perm, r_ij, rowstart, tabI, flag, d_out, N);
}

// Round 6
// 239.656 us; speedup vs baseline: 1.5267x; 1.5267x over previous
//
#include <hip/hip_runtime.h>
#include <hip/hip_bf16.h>
#include <hip/hip_fp16.h>
#include <math.h>

// ---------------------------------------------------------------------------
// DisplacementTensors: rad = MLP(radial_encode(|r|)) depends only on |r| ->
// tabulate [F(d) | F(d)@w_v | F(d)@w_d] (96 f32/row, 8192 nearest-neighbor
// entries, 3 MB, L2-resident).  k_table parallelized over (entry x neuron):
// 4 entries/block, lane = output neuron, weights via coalesced vector loads,
// activations in per-entry LDS.  CSR segment-sum: rank(atomic) -> scan ->
// place packed 8B payload (f16 rs | u16 idx) in CSR order -> one wave per
// node streams its slice, branch-free accumulate, direct output writes.
// dtype (bf16 vs f32) detected by probing r_ij halfwords (this dataset: f32).
// ---------------------------------------------------------------------------

#define TSIZE 8192
#define DMAX  2.0f           // RBF centers <=1, width 1/8 -> F const beyond ~2
#define NPB   4              // nodes (waves) per block in k_nodes
#define EPB   4              // entries per block in k_table

// f32 concat-weight offsets (floats)
#define O_WRAD 0
#define O_BRAD 256
#define O_WDIR 288
#define O_W1   1312
#define O_B1   3360
#define O_W2   3424
#define O_B2   7520
#define O_W3   7584
#define O_B3   9632
#define O_WV   9664
#define O_WD   10688
#define W_TOT  11712

__device__ __forceinline__ float lrelu(float x) { return x > 0.0f ? x : 0.1f * x; }

__device__ __forceinline__ float ldf(const void* p, int i, bool f32) {
    return f32 ? ((const float*)p)[i]
               : __uint_as_float(((unsigned int)((const unsigned short*)p)[i]) << 16);
}
__device__ __forceinline__ void stf(void* p, size_t i, float v, bool f32) {
    if (f32) ((float*)p)[i] = v;
    else     ((__hip_bfloat16*)p)[i] = __float2bfloat16(v);
}

// probe first 128 halfwords of r_ij as bf16: f32 data's low halves have random
// exponents -> non-finite/huge values appear with P ~ 1-1e-16.
__device__ __forceinline__ bool detect_f32(const void* r) {
    const unsigned short* p = (const unsigned short*)r;
    int bad = 0;
#pragma unroll 8
    for (int i = 0; i < 128; i++) {
        float v = __uint_as_float(((unsigned int)p[i]) << 16);
        bad |= (!isfinite(v) || fabsf(v) > 1e5f) ? 1 : 0;
    }
    return bad != 0;
}

// --- fused prep: flag store | weight->f32 concat | zero counts -------------
__global__ void k_prep(const void* __restrict__ r_ij,
                       const void* w_rad, const void* b_rad, const void* w_direct,
                       const void* w1, const void* b1, const void* w2, const void* b2,
                       const void* w3, const void* b3, const void* w_v, const void* w_d,
                       float* __restrict__ wcat, int* __restrict__ flag,
                       int* __restrict__ counts, int N) {
    const int b = blockIdx.x;
    if (b == 0) {
        if (threadIdx.x == 0) flag[0] = detect_f32(r_ij) ? 1 : 0;
    } else if (b <= 11) {
        const bool f32 = detect_f32(r_ij);
        const void* src; int cnt; int off;
        switch (b) {
            case 1:  src = w_rad;    cnt = 256;  off = O_WRAD; break;
            case 2:  src = b_rad;    cnt = 32;   off = O_BRAD; break;
            case 3:  src = w_direct; cnt = 1024; off = O_WDIR; break;
            case 4:  src = w1;       cnt = 2048; off = O_W1;   break;
            case 5:  src = b1;       cnt = 64;   off = O_B1;   break;
            case 6:  src = w2;       cnt = 4096; off = O_W2;   break;
            case 7:  src = b2;       cnt = 64;   off = O_B2;   break;
            case 8:  src = w3;       cnt = 2048; off = O_W3;   break;
            case 9:  src = b3;       cnt = 32;   off = O_B3;   break;
            case 10: src = w_v;      cnt = 1024; off = O_WV;   break;
            default: src = w_d;      cnt = 1024; off = O_WD;   break;
        }
        for (int i = threadIdx.x; i < cnt; i += blockDim.x)
            wcat[off + i] = ldf(src, i, f32);
    } else {
        int i = (b - 12) * blockDim.x + threadIdx.x;
        if (i < N) counts[i] = 0;
    }
}

// --- LUT build: 4 entries/block, wave = entry, lane = neuron ---------------
// Weight loads are lane-varying (coalesced vector loads, deeply pipelined);
// activations in per-entry LDS slices (wave-uniform broadcast reads).
__global__ void __launch_bounds__(64 * EPB) k_table(const float* __restrict__ wcat,
                                                    float* __restrict__ tabI) {
    __shared__ float Lh[EPB][32], Lt1[EPB][64], Lt2[EPB][64], Lrad[EPB][32];

    const int s = threadIdx.x >> 6;          // entry slot (== wave id)
    const int j = threadIdx.x & 63;          // neuron
    const int e = blockIdx.x * EPB + s;
    const float d = (float)e * (DMAX / (float)(TSIZE - 1));

    float enc[8];
#pragma unroll
    for (int k = 0; k < 8; k++) {
        float t = (d - (float)k * (1.0f / 7.0f)) * 8.0f;
        enc[k] = expf(-t * t);
    }

    if (j < 32) {                            // h = enc @ w_rad + b_rad
        float hv = wcat[O_BRAD + j];
#pragma unroll
        for (int k = 0; k < 8; k++) hv = fmaf(enc[k], wcat[O_WRAD + k * 32 + j], hv);
        Lh[s][j] = hv;
    }
    __syncthreads();

    {                                        // t1 = lrelu(h @ w1 + b1)
        float v = wcat[O_B1 + j];
#pragma unroll
        for (int i = 0; i < 32; i++) v = fmaf(Lh[s][i], wcat[O_W1 + i * 64 + j], v);
        Lt1[s][j] = lrelu(v);
    }
    __syncthreads();

    {                                        // t2 = lrelu(t1 @ w2 + b2)
        float v = wcat[O_B2 + j];
#pragma unroll
        for (int i = 0; i < 64; i++) v = fmaf(Lt1[s][i], wcat[O_W2 + i * 64 + j], v);
        Lt2[s][j] = lrelu(v);
    }
    __syncthreads();

    if (j < 32) {                            // rad = h@w_direct + t2@w3 + b3
        float v = wcat[O_B3 + j];
#pragma unroll
        for (int i = 0; i < 64; i++) v = fmaf(Lt2[s][i], wcat[O_W3 + i * 32 + j], v);
#pragma unroll
        for (int i = 0; i < 32; i++) v = fmaf(Lh[s][i], wcat[O_WDIR + i * 32 + j], v);
        Lrad[s][j] = v;
        tabI[e * 96 + j] = v;
    }
    __syncthreads();

    if (j < 32) {                            // folded output transforms
        float sv = 0.0f, sd = 0.0f;
#pragma unroll
        for (int i = 0; i < 32; i++) {
            float ri = Lrad[s][i];
            sv = fmaf(ri, wcat[O_WV + i * 32 + j], sv);
            sd = fmaf(ri, wcat[O_WD + i * 32 + j], sd);
        }
        tabI[e * 96 + 32 + j] = sv;
        tabI[e * 96 + 64 + j] = sd;
    }
}

// --- CSR construction ------------------------------------------------------
// rank[e] = within-node arrival order (single atomic pass)
__global__ void k_rank(const int* __restrict__ src, int* __restrict__ counts,
                       int* __restrict__ rank, int E) {
    int e = blockIdx.x * blockDim.x + threadIdx.x;
    if (e < E) rank[e] = atomicAdd(&counts[src[e]], 1);
}

__global__ void k_scan(const int* __restrict__ counts, int* __restrict__ rowstart,
                       int N, int E) {
    __shared__ int part[1024];
    const int t = threadIdx.x;
    const int CH = (N + 1023) / 1024;
    const int lo = t * CH;
    const int hi = min(lo + CH, N);

    int s = 0;
    for (int i = lo; i < hi; i++) s += counts[i];
    part[t] = s;
    __syncthreads();

    for (int off = 1; off < 1024; off <<= 1) {
        int v = part[t];
        int w = (t >= off) ? part[t - off] : 0;
        __syncthreads();
        part[t] = v + w;
        __syncthreads();
    }

    int run = (t == 0) ? 0 : part[t - 1];
    for (int i = lo; i < hi; i++) {
        rowstart[i] = run;
        run += counts[i];
    }
    if (t == 0) rowstart[N] = E;
}

// place packed payload into CSR slot (plain store; rank precomputed)
__global__ void k_place(const int* __restrict__ src, const int* __restrict__ rank,
                        const int* __restrict__ rowstart,
                        const void* __restrict__ r_ij, const int* __restrict__ flag,
                        uint2* __restrict__ eps, int* __restrict__ perm, int E) {
    int e = blockIdx.x * blockDim.x + threadIdx.x;
    if (e >= E) return;
    const int pos = rowstart[src[e]] + rank[e];
    if (eps) {
        const bool f32 = flag[0] != 0;
        const float x = ldf(r_ij, 3 * e + 0, f32);
        const float y = ldf(r_ij, 3 * e + 1, f32);
        const float z = ldf(r_ij, 3 * e + 2, f32);
        const float d2 = x * x + y * y + z * z;
        const float inv = rsqrtf(1.0f + 49.0f * d2);     // tens_sigmoid(7*r)
        const float u = fminf(sqrtf(d2), DMAX) * ((float)(TSIZE - 1) / DMAX);
        const unsigned int ti = (unsigned int)(u + 0.5f); // nearest, <= TSIZE-1
        const unsigned int h0 = __half_as_ushort(__float2half(7.0f * x * inv));
        const unsigned int h1 = __half_as_ushort(__float2half(7.0f * y * inv));
        const unsigned int h2 = __half_as_ushort(__float2half(7.0f * z * inv));
        eps[pos] = make_uint2(h0 | (h1 << 16), h2 | (ti << 16));
    } else {
        perm[pos] = e;
    }
}

// --- per-node accumulation: one wave per node, branch-free -----------------
// lane = (a = lane&31) x (half = lane>>5).
// b1 = (half? rd : rv)*(half? rs1 : 1);  b2 = rd*(half? rs2 : rs0).
__global__ void __launch_bounds__(64 * NPB) k_nodes(
    const uint2* __restrict__ eps,
    const int* __restrict__ perm,
    const void* __restrict__ r_ij,
    const int* __restrict__ rowstart,
    const float* __restrict__ tabI,
    const int* __restrict__ flag,
    void* __restrict__ out, int N) {
    const int wave = threadIdx.x >> 6;
    const int lane = threadIdx.x & 63;
    const int n = blockIdx.x * NPB + wave;
    if (n >= N) return;
    const int a = lane & 31;
    const bool hi = (lane >> 5) != 0;
    const bool f32 = flag[0] != 0;

    const int s0 = rowstart[n];
    const int s1 = rowstart[n + 1];

    float accR = 0.f, acc1 = 0.f, acc2 = 0.f, acc3 = 0.f,
          acc4 = 0.f, acc5 = 0.f, acc6 = 0.f;

    if (eps) {
        int idx = s0;
        for (; idx + 1 < s1; idx += 2) {          // unroll x2: overlap loads
            const uint2 qa = eps[idx];
            const uint2 qb = eps[idx + 1];
            const float ax = __half2float(__ushort_as_half((unsigned short)(qa.x & 0xffff)));
            const float ay = __half2float(__ushort_as_half((unsigned short)(qa.x >> 16)));
            const float az = __half2float(__ushort_as_half((unsigned short)(qa.y & 0xffff)));
            const int   ab = (int)(qa.y >> 16) * 96 + a;
            const float bx = __half2float(__ushort_as_half((unsigned short)(qb.x & 0xffff)));
            const float by = __half2float(__ushort_as_half((unsigned short)(qb.x >> 16)));
            const float bz = __half2float(__ushort_as_half((unsigned short)(qb.y & 0xffff)));
            const int   bb = (int)(qb.y >> 16) * 96 + a;

            const float raA = tabI[ab], rvA = tabI[ab + 32], rdA = tabI[ab + 64];
            const float raB = tabI[bb], rvB = tabI[bb + 32], rdB = tabI[bb + 64];

            const float b1A = (hi ? rdA : rvA) * (hi ? ay : 1.0f);
            const float b2A = rdA * (hi ? az : ax);
            const float b1B = (hi ? rdB : rvB) * (hi ? by : 1.0f);
            const float b2B = rdB * (hi ? bz : bx);

            accR += raA + raB;
            acc1 += b1A * ax + b1B * bx;
            acc2 += b1A * ay + b1B * by;
            acc3 += b1A * az + b1B * bz;
            acc4 += b2A * ax + b2B * bx;
            acc5 += b2A * ay + b2B * by;
            acc6 += b2A * az + b2B * bz;
        }
        if (idx < s1) {
            const uint2 q = eps[idx];
            const float x = __half2float(__ushort_as_half((unsigned short)(q.x & 0xffff)));
            const float y = __half2float(__ushort_as_half((unsigned short)(q.x >> 16)));
            const float z = __half2float(__ushort_as_half((unsigned short)(q.y & 0xffff)));
            const int   b = (int)(q.y >> 16) * 96 + a;
            const float ra = tabI[b], rv = tabI[b + 32], rd = tabI[b + 64];
            const float b1 = (hi ? rd : rv) * (hi ? y : 1.0f);
            const float b2 = rd * (hi ? z : x);
            accR += ra;
            acc1 += b1 * x; acc2 += b1 * y; acc3 += b1 * z;
            acc4 += b2 * x; acc5 += b2 * y; acc6 += b2 * z;
        }
    } else {
        for (int idx = s0; idx < s1; idx++) {
            const int e = perm[idx];
            const float x0 = ldf(r_ij, 3 * e + 0, f32);
            const float y0 = ldf(r_ij, 3 * e + 1, f32);
            const float z0 = ldf(r_ij, 3 * e + 2, f32);
            const float d2 = x0 * x0 + y0 * y0 + z0 * z0;
            const float inv = rsqrtf(1.0f + 49.0f * d2);
            const float x = 7.0f * x0 * inv, y = 7.0f * y0 * inv, z = 7.0f * z0 * inv;
            const float u = fminf(sqrtf(d2), DMAX) * ((float)(TSIZE - 1) / DMAX);
            const int b = (int)(u + 0.5f) * 96 + a;
            const float ra = tabI[b], rv = tabI[b + 32], rd = tabI[b + 64];
            const float b1 = (hi ? rd : rv) * (hi ? y : 1.0f);
            const float b2 = rd * (hi ? z : x);
            accR += ra;
            acc1 += b1 * x; acc2 += b1 * y; acc3 += b1 * z;
            acc4 += b2 * x; acc5 += b2 * y; acc6 += b2 * z;
        }
    }

    const size_t baseV = (size_t)N * 32;
    const size_t baseD = (size_t)N * 128;
    if (!hi) {
        stf(out, (size_t)n * 32 + a, accR, f32);
        const size_t vb = baseV + (size_t)n * 96 + a * 3;
        stf(out, vb + 0, acc1, f32);
        stf(out, vb + 1, acc2, f32);
        stf(out, vb + 2, acc3, f32);
        const size_t db = baseD + (size_t)n * 288 + a * 9;
        stf(out, db + 0, acc4, f32);
        stf(out, db + 1, acc5, f32);
        stf(out, db + 2, acc6, f32);
    } else {
        const size_t db = baseD + (size_t)n * 288 + a * 9;
        stf(out, db + 3, acc1, f32);
        stf(out, db + 4, acc2, f32);
        stf(out, db + 5, acc3, f32);
        stf(out, db + 6, acc4, f32);
        stf(out, db + 7, acc5, f32);
        stf(out, db + 8, acc6, f32);
    }
}

extern "C" void kernel_launch(void* const* d_in, const int* in_sizes, int n_in,
                              void* d_out, int out_size, void* d_ws, size_t ws_size,
                              hipStream_t stream) {
    const void* r_ij     = d_in[0];
    const void* w_rad    = d_in[1];
    const void* b_rad    = d_in[2];
    const void* w_direct = d_in[3];
    const void* w1       = d_in[4];
    const void* b1       = d_in[5];
    const void* w2       = d_in[6];
    const void* b2       = d_in[7];
    const void* w3       = d_in[8];
    const void* b3       = d_in[9];
    const void* w_v      = d_in[10];
    const void* w_d      = d_in[11];
    const int* edges_src = (const int*)d_in[12];

    const int E = in_sizes[12];
    const int N = out_size / 416;   // 32 + 96 + 288 per node

    // layout: [eps|perm slot] wcat flag tabI counts rowstart rank
    const size_t fixedInts = (size_t)W_TOT + 4 + (size_t)TSIZE * 96
                           + (size_t)N + (size_t)(N + 1) + (size_t)E;
    const size_t epsBytes  = (size_t)E * 8;
    const bool use_eps = ws_size >= epsBytes + fixedInts * 4 + 64;

    char* w = (char*)d_ws;
    uint2* eps = use_eps ? (uint2*)w : nullptr;
    int* perm  = use_eps ? nullptr : (int*)w;           // fallback slot
    const size_t slotBytes = use_eps ? epsBytes : (size_t)E * 4;

    float* wcat   = (float*)(w + ((slotBytes + 15) & ~(size_t)15));
    int* flag     = (int*)(wcat + W_TOT);
    float* tabI   = (float*)(flag + 4);
    int* counts   = (int*)(tabI + (size_t)TSIZE * 96);
    int* rowstart = counts + N;           // N+1
    int* rank     = rowstart + N + 1;     // E

    k_prep<<<12 + (N + 255) / 256, 256, 0, stream>>>(
        r_ij, w_rad, b_rad, w_direct, w1, b1, w2, b2, w3, b3, w_v, w_d,
        wcat, flag, counts, N);
    k_table<<<TSIZE / EPB, 64 * EPB, 0, stream>>>(wcat, tabI);
    k_rank<<<(E + 255) / 256, 256, 0, stream>>>(edges_src, counts, rank, E);
    k_scan<<<1, 1024, 0, stream>>>(counts, rowstart, N, E);
    k_place<<<(E + 255) / 256, 256, 0, stream>>>(edges_src, rank, rowstart,
                                                 r_ij, flag, eps, perm, E);
    k_nodes<<<(N + NPB - 1) / NPB, 64 * NPB, 0, stream>>>(
        eps, perm, r_ij, rowstart, tabI, flag, d_out, N);
}